// Round 9
// baseline (148.143 us; speedup 1.0000x reference)
//
#include <hip/hip_runtime.h>
#include <hip/hip_bf16.h>

#define NN    50000
#define EE    1600000
#define IND   128
#define OUTD  64
#define SLOPE 0.1f

// fine buckets (aggregate granularity)
#define BSH    5                   // log2(nodes per fine bucket)
#define BW     32                  // nodes per fine bucket
#define NB     1564                // ceil(NN / 32) aggregate blocks
#define NFINE  1568                // NC * 8 fine regions allocated
#define CAP    1408                // fine capacity: mean 1024 + 12 sigma
#define CAPT   6                   // ceil(CAP/256) register stash bound
// coarse buckets
#define CSH    8                   // log2(nodes per coarse bucket)
#define NC     196                 // ceil(NN / 256)
#define CAP1   8832                // coarse capacity: mean 8192 + 7 sigma
#define NBLK1  500
#define CHUNK1 (EE / NBLK1)        // 3200 edges per coarse block
#define NSPLIT 4
#define SCAP   (CAP1 / NSPLIT)     // 2208: deterministic stage bound
#define NLIN   (NN / 16)           // 3125 linear blocks

typedef __attribute__((ext_vector_type(8))) short short8;
typedef __attribute__((ext_vector_type(4))) float float4v;

// ---------------------------------------------------------------------------
// Fused K1 (round-2 verified best, untouched): blocks [0,NBLK1) = coarse bin;
// blocks [NBLK1, NBLK1+NLIN) = MFMA linear. Barriers block-uniform.
// ---------------------------------------------------------------------------
union SMem {
    struct {
        ushort xs[16 * 136];        // x tile bf16 (pad 8/row)
        ushort wt[64 * 136];        // W bf16
        float  newt[16 * 68];       // fp32 out tile (pad 4)
    } lin;
    int h[NC];                      // coarse histogram/cursors
};

__global__ __launch_bounds__(256) void fused_lincoarse_kernel(
    const float* __restrict__ x, const float* __restrict__ W,
    const float* __restrict__ bias, const float* __restrict__ a,
    const int* __restrict__ ei, int* __restrict__ gcur1,
    unsigned* __restrict__ ebuf1,
    ushort* __restrict__ nbuf2, float* __restrict__ s_src, float* __restrict__ s_dst)
{
    __shared__ SMem sm;
    const int tid = threadIdx.x;

    if (blockIdx.x < NBLK1) {
        // ----- coarse bin: 196 buckets of 256 nodes; runs ~16 = full lines
        int* h = sm.h;
        for (int i = tid; i < NC; i += 256) h[i] = 0;
        __syncthreads();
        const int base = blockIdx.x * CHUNK1;
        const int4* s4p = (const int4*)(ei + base);
        for (int i = tid; i < CHUNK1 / 4; i += 256) {
            int4 s4 = s4p[i];
            atomicAdd(&h[s4.x >> CSH], 1);
            atomicAdd(&h[s4.y >> CSH], 1);
            atomicAdd(&h[s4.z >> CSH], 1);
            atomicAdd(&h[s4.w >> CSH], 1);
        }
        __syncthreads();
        for (int i = tid; i < NC; i += 256) {
            int c = h[i];
            if (c) h[i] = i * CAP1 + atomicAdd(&gcur1[i * 16], c);
        }
        __syncthreads();
        const int4* d4p = (const int4*)(ei + EE + base);
        for (int i = tid; i < CHUNK1 / 4; i += 256) {
            int4 s4 = s4p[i];
            int4 d4 = d4p[i];
            int p0 = atomicAdd(&h[s4.x >> CSH], 1);
            int p1 = atomicAdd(&h[s4.y >> CSH], 1);
            int p2 = atomicAdd(&h[s4.z >> CSH], 1);
            int p3 = atomicAdd(&h[s4.w >> CSH], 1);
            ebuf1[p0] = ((unsigned)(s4.x & 255) << 16) | (unsigned)d4.x;
            ebuf1[p1] = ((unsigned)(s4.y & 255) << 16) | (unsigned)d4.y;
            ebuf1[p2] = ((unsigned)(s4.z & 255) << 16) | (unsigned)d4.z;
            ebuf1[p3] = ((unsigned)(s4.w & 255) << 16) | (unsigned)d4.w;
        }
        return;
    }

    // ----- MFMA linear: new = x@W.T + b, bf16 out + fused score dots
    const int node0 = (blockIdx.x - NBLK1) * 16;
    const float4* W4 = (const float4*)W;
    #pragma unroll
    for (int i = 0; i < 8; ++i) {
        int idx = tid + i * 256;
        float4 wv = W4[idx];
        int n = idx >> 5, k = (idx & 31) * 4;
        ushort4 pk; __hip_bfloat16 h;
        h = __float2bfloat16(wv.x); pk.x = *(ushort*)&h;
        h = __float2bfloat16(wv.y); pk.y = *(ushort*)&h;
        h = __float2bfloat16(wv.z); pk.z = *(ushort*)&h;
        h = __float2bfloat16(wv.w); pk.w = *(ushort*)&h;
        *(ushort4*)&sm.lin.wt[n * 136 + k] = pk;
    }
    const float4* x4 = (const float4*)(x + (size_t)node0 * IND);
    #pragma unroll
    for (int i = 0; i < 2; ++i) {
        int idx = tid + i * 256;
        float4 xv = x4[idx];
        int r = idx >> 5, cc = (idx & 31) * 4;
        ushort4 pk; __hip_bfloat16 h;
        h = __float2bfloat16(xv.x); pk.x = *(ushort*)&h;
        h = __float2bfloat16(xv.y); pk.y = *(ushort*)&h;
        h = __float2bfloat16(xv.z); pk.z = *(ushort*)&h;
        h = __float2bfloat16(xv.w); pk.w = *(ushort*)&h;
        *(ushort4*)&sm.lin.xs[r * 136 + cc] = pk;
    }
    __syncthreads();

    const int w    = tid >> 6;
    const int lane = tid & 63;
    const int q    = lane >> 4;
    const int m16  = lane & 15;
    float4v acc = {0.f, 0.f, 0.f, 0.f};
    #pragma unroll
    for (int kk = 0; kk < IND; kk += 32) {
        short8 af = *(const short8*)&sm.lin.xs[m16 * 136 + kk + q * 8];
        short8 bf = *(const short8*)&sm.lin.wt[(w * 16 + m16) * 136 + kk + q * 8];
        acc = __builtin_amdgcn_mfma_f32_16x16x32_bf16(af, bf, acc, 0, 0, 0);
    }
    const float bv = bias[w * 16 + m16];
    #pragma unroll
    for (int r = 0; r < 4; ++r)         // D: col=lane&15, row=quad*4+r
        sm.lin.newt[(q * 4 + r) * 68 + w * 16 + m16] = acc[r] + bv;
    __syncthreads();

    const int nl = tid >> 4;
    const int jg = tid & 15;
    const int j0 = jg * 4;
    float4 va = *(const float4*)&sm.lin.newt[nl * 68 + j0];
    const int n = node0 + nl;
    ushort4 pk;
    { __hip_bfloat16 h;
      h = __float2bfloat16(va.x); pk.x = *(ushort*)&h;
      h = __float2bfloat16(va.y); pk.y = *(ushort*)&h;
      h = __float2bfloat16(va.z); pk.z = *(ushort*)&h;
      h = __float2bfloat16(va.w); pk.w = *(ushort*)&h; }
    *(ushort4*)&nbuf2[(size_t)n * OUTD + j0] = pk;

    float ss = va.x * a[j0]        + va.y * a[j0 + 1]
             + va.z * a[j0 + 2]    + va.w * a[j0 + 3];
    float sd = va.x * a[OUTD + j0]     + va.y * a[OUTD + j0 + 1]
             + va.z * a[OUTD + j0 + 2] + va.w * a[OUTD + j0 + 3];
    #pragma unroll
    for (int m = 1; m < 16; m <<= 1) {
        ss += __shfl_xor(ss, m, 64);
        sd += __shfl_xor(sd, m, 64);
    }
    if (jg == 0) { s_src[n] = ss; s_dst[n] = sd; }
}

// ---------------------------------------------------------------------------
// Pass 2: fine bin + EXP FUSION. The sort passes are the round-2 verified
// structure; the scatter pass now also computes ev = exp(leakyrelu(score))
// — K2's LDS-atomic serialization leaves its VMEM/VALU idle, so the random
// s_dst gather + exp hide in those bubbles, and K3's phase A (which did this
// work with only 6-deep pipelining) collapses to load+histogram.
// ebuf2 entry: uint2 { (ln<<21) | (d<<4), bits(ev) } — d pre-shifted for
// K3's gather. Writes stay fully coalesced (~2 KB runs of 8-B entries).
// ---------------------------------------------------------------------------
__global__ __launch_bounds__(256) void finebin_kernel(
    const unsigned* __restrict__ ebuf1, const int* __restrict__ gcur1,
    const float* __restrict__ s_src, const float* __restrict__ s_dst,
    int* __restrict__ gcur2, uint2* __restrict__ ebuf2)
{
    __shared__ uint2 stage[SCAP];       // 17.7 KB
    __shared__ float ssL[256];          // this coarse bucket's s_src (1 KB)
    __shared__ int h[8], lofs[8], grun[8], cur[8];
    const int tid = threadIdx.x;
    const int c   = blockIdx.x >> 2;
    const int sp  = blockIdx.x & 3;
    const int cnt1 = gcur1[c * 16];
    const int seg  = (cnt1 + NSPLIT - 1) / NSPLIT;
    const int lo   = sp * seg;
    const int m    = max(0, min(cnt1, lo + seg) - lo);
    if (tid < 8) h[tid] = 0;
    {
        int n = c * 256 + tid;
        ssL[tid] = (n < NN) ? s_src[n] : 0.f;
    }
    __syncthreads();
    const unsigned* eb = ebuf1 + (size_t)c * CAP1 + lo;
    for (int i = tid; i < m; i += 256)
        atomicAdd(&h[eb[i] >> 21], 1);          // sub = bits 21..23
    __syncthreads();
    if (tid == 0) {
        int run = 0;
        #pragma unroll
        for (int f = 0; f < 8; ++f) { lofs[f] = run; run += h[f]; }
    }
    __syncthreads();
    if (tid < 8) {
        cur[tid]  = lofs[tid];
        grun[tid] = atomicAdd(&gcur2[(c * 8 + tid) * 16], h[tid]);
    }
    __syncthreads();
    for (int i = tid; i < m; i += 256) {        // scatter + fused exp
        unsigned e = eb[i];
        unsigned d = e & 0xFFFFu;
        float sc = ssL[(e >> 16) & 255u] + s_dst[d];
        float lr = sc > 0.f ? sc : SLOPE * sc;
        float ev = __expf(lr);
        int pos = atomicAdd(&cur[e >> 21], 1);
        stage[pos] = make_uint2((((e >> 16) & 31u) << 21) | (d << 4),
                                __float_as_uint(ev));
    }
    __syncthreads();
    #pragma unroll 1
    for (int f = 0; f < 8; ++f) {
        const int cf = h[f];
        uint2* dst = ebuf2 + (size_t)(c * 8 + f) * CAP + grun[f];
        const uint2* sp2 = stage + lofs[f];
        for (int i = tid; i < cf; i += 256) dst[i] = sp2[i];   // coalesced
    }
}

// ---------------------------------------------------------------------------
// Fused aggregate v11: phase A is now just {uint2 load -> histogram atomic}
// (exp + s_dst gather moved to K2); phase C masks out the pre-shifted d<<4.
// Phase D identical to the R8-verified hot loop (dual chains, 32-deep
// cascade, nbufq[p.x + c16]).
// ---------------------------------------------------------------------------
__global__ __launch_bounds__(256) void aggregate_kernel(
    const uint2* __restrict__ ebuf, const int* __restrict__ gcur,
    const ushort* __restrict__ nbuf2, float* __restrict__ out)
{
    __shared__ uint2 pairs[CAP];        // {d<<4, bits(ev)} sorted by node
    __shared__ int cntL[BW], ofs[BW], cur[BW];
    const int tid  = threadIdx.x;
    const int wid  = tid >> 6;
    const int lane = tid & 63;
    const int b    = blockIdx.x;
    const int n0   = b << BSH;
    const uint2* __restrict__ nbufq = (const uint2*)nbuf2;  // row = 16 uint2

    if (tid < BW) cntL[tid] = 0;
    __syncthreads();

    const int cnt = gcur[b * 16];
    const uint2* eb = ebuf + (size_t)b * CAP;

    uint2 er2[CAPT];
    #pragma unroll
    for (int k = 0; k < CAPT; ++k) {              // phase A: load + histogram
        int i = tid + k * 256;
        if (i < cnt) {
            uint2 e = eb[i];
            er2[k] = e;
            atomicAdd(&cntL[e.x >> 21], 1);
        }
    }
    __syncthreads();

    if (wid == 0) {                               // 32-ctr exclusive scan
        int c = (lane < BW) ? cntL[lane] : 0;
        int sc = c;
        #pragma unroll
        for (int m = 1; m < BW; m <<= 1) {
            int v = __shfl_up(sc, m, 64);
            if (lane >= m) sc += v;
        }
        if (lane < BW) { ofs[lane] = sc - c; cur[lane] = sc - c; }
    }
    __syncthreads();

    #pragma unroll
    for (int k = 0; k < CAPT; ++k) {              // phase C: sorted LDS scatter
        int i = tid + k * 256;
        if (i < cnt) {
            int ln = er2[k].x >> 21;
            int pos = atomicAdd(&cur[ln], 1);
            pairs[pos] = make_uint2(er2[k].x & 0xFFFF0u, er2[k].y);
        }
    }
    __syncthreads();

    const int e16 = lane >> 4;                    // quarter: edge offset
    const int c16 = lane & 15;                    // 4-dim group (uint2)

    #pragma unroll 1
    for (int t = 0; t < BW / 4; ++t) {            // wave's 8 nodes
        const int ln  = wid * (BW / 4) + t;
        const int beg = ofs[ln];
        const int len = cntL[ln];

        float a0 = 0.f, a1 = 0.f, a2 = 0.f, a3 = 0.f, es0 = 0.f;
        float b0 = 0.f, b1 = 0.f, b2 = 0.f, b3 = 0.f, es1 = 0.f;
        int j = 0;
        for (; j + 32 <= len; j += 32) {          // 32 edges: 8 per quarter
            uint2 pA = pairs[beg + j + 0  + e16];
            uint2 pB = pairs[beg + j + 4  + e16];
            uint2 pC = pairs[beg + j + 8  + e16];
            uint2 pD = pairs[beg + j + 12 + e16];
            uint2 pE = pairs[beg + j + 16 + e16];
            uint2 pF = pairs[beg + j + 20 + e16];
            uint2 pG = pairs[beg + j + 24 + e16];
            uint2 pH = pairs[beg + j + 28 + e16];
            uint2 gA = nbufq[pA.x + c16];
            uint2 gB = nbufq[pB.x + c16];
            uint2 gC = nbufq[pC.x + c16];
            uint2 gD = nbufq[pD.x + c16];
            uint2 gE = nbufq[pE.x + c16];
            uint2 gF = nbufq[pF.x + c16];
            uint2 gG = nbufq[pG.x + c16];
            uint2 gH = nbufq[pH.x + c16];
            float fA = __uint_as_float(pA.y), fB = __uint_as_float(pB.y);
            float fC = __uint_as_float(pC.y), fD = __uint_as_float(pD.y);
            float fE = __uint_as_float(pE.y), fF = __uint_as_float(pF.y);
            float fG = __uint_as_float(pG.y), fH = __uint_as_float(pH.y);
            es0 += (fA + fB) + (fC + fD);
            es1 += (fE + fF) + (fG + fH);
            a0 = fmaf(fA, __uint_as_float(gA.x << 16), a0);
            a1 = fmaf(fA, __uint_as_float(gA.x & 0xFFFF0000u), a1);
            a2 = fmaf(fA, __uint_as_float(gA.y << 16), a2);
            a3 = fmaf(fA, __uint_as_float(gA.y & 0xFFFF0000u), a3);
            a0 = fmaf(fB, __uint_as_float(gB.x << 16), a0);
            a1 = fmaf(fB, __uint_as_float(gB.x & 0xFFFF0000u), a1);
            a2 = fmaf(fB, __uint_as_float(gB.y << 16), a2);
            a3 = fmaf(fB, __uint_as_float(gB.y & 0xFFFF0000u), a3);
            a0 = fmaf(fC, __uint_as_float(gC.x << 16), a0);
            a1 = fmaf(fC, __uint_as_float(gC.x & 0xFFFF0000u), a1);
            a2 = fmaf(fC, __uint_as_float(gC.y << 16), a2);
            a3 = fmaf(fC, __uint_as_float(gC.y & 0xFFFF0000u), a3);
            a0 = fmaf(fD, __uint_as_float(gD.x << 16), a0);
            a1 = fmaf(fD, __uint_as_float(gD.x & 0xFFFF0000u), a1);
            a2 = fmaf(fD, __uint_as_float(gD.y << 16), a2);
            a3 = fmaf(fD, __uint_as_float(gD.y & 0xFFFF0000u), a3);
            b0 = fmaf(fE, __uint_as_float(gE.x << 16), b0);
            b1 = fmaf(fE, __uint_as_float(gE.x & 0xFFFF0000u), b1);
            b2 = fmaf(fE, __uint_as_float(gE.y << 16), b2);
            b3 = fmaf(fE, __uint_as_float(gE.y & 0xFFFF0000u), b3);
            b0 = fmaf(fF, __uint_as_float(gF.x << 16), b0);
            b1 = fmaf(fF, __uint_as_float(gF.x & 0xFFFF0000u), b1);
            b2 = fmaf(fF, __uint_as_float(gF.y << 16), b2);
            b3 = fmaf(fF, __uint_as_float(gF.y & 0xFFFF0000u), b3);
            b0 = fmaf(fG, __uint_as_float(gG.x << 16), b0);
            b1 = fmaf(fG, __uint_as_float(gG.x & 0xFFFF0000u), b1);
            b2 = fmaf(fG, __uint_as_float(gG.y << 16), b2);
            b3 = fmaf(fG, __uint_as_float(gG.y & 0xFFFF0000u), b3);
            b0 = fmaf(fH, __uint_as_float(gH.x << 16), b0);
            b1 = fmaf(fH, __uint_as_float(gH.x & 0xFFFF0000u), b1);
            b2 = fmaf(fH, __uint_as_float(gH.y << 16), b2);
            b3 = fmaf(fH, __uint_as_float(gH.y & 0xFFFF0000u), b3);
        }
        for (; j + 16 <= len; j += 16) {          // 16 edges: 4 per quarter
            uint2 pA = pairs[beg + j + 0  + e16];
            uint2 pB = pairs[beg + j + 4  + e16];
            uint2 pC = pairs[beg + j + 8  + e16];
            uint2 pD = pairs[beg + j + 12 + e16];
            uint2 gA = nbufq[pA.x + c16];
            uint2 gB = nbufq[pB.x + c16];
            uint2 gC = nbufq[pC.x + c16];
            uint2 gD = nbufq[pD.x + c16];
            float fA = __uint_as_float(pA.y), fB = __uint_as_float(pB.y);
            float fC = __uint_as_float(pC.y), fD = __uint_as_float(pD.y);
            es0 += fA + fB;
            es1 += fC + fD;
            a0 = fmaf(fA, __uint_as_float(gA.x << 16), a0);
            a1 = fmaf(fA, __uint_as_float(gA.x & 0xFFFF0000u), a1);
            a2 = fmaf(fA, __uint_as_float(gA.y << 16), a2);
            a3 = fmaf(fA, __uint_as_float(gA.y & 0xFFFF0000u), a3);
            a0 = fmaf(fB, __uint_as_float(gB.x << 16), a0);
            a1 = fmaf(fB, __uint_as_float(gB.x & 0xFFFF0000u), a1);
            a2 = fmaf(fB, __uint_as_float(gB.y << 16), a2);
            a3 = fmaf(fB, __uint_as_float(gB.y & 0xFFFF0000u), a3);
            b0 = fmaf(fC, __uint_as_float(gC.x << 16), b0);
            b1 = fmaf(fC, __uint_as_float(gC.x & 0xFFFF0000u), b1);
            b2 = fmaf(fC, __uint_as_float(gC.y << 16), b2);
            b3 = fmaf(fC, __uint_as_float(gC.y & 0xFFFF0000u), b3);
            b0 = fmaf(fD, __uint_as_float(gD.x << 16), b0);
            b1 = fmaf(fD, __uint_as_float(gD.x & 0xFFFF0000u), b1);
            b2 = fmaf(fD, __uint_as_float(gD.y << 16), b2);
            b3 = fmaf(fD, __uint_as_float(gD.y & 0xFFFF0000u), b3);
        }
        for (; j < len; j += 4) {                 // tail: clamp + mask
            int idx = j + e16;
            uint2 p = pairs[beg + min(idx, len - 1)];
            float f = (idx < len) ? __uint_as_float(p.y) : 0.f;
            uint2 g = nbufq[p.x + c16];
            es0 += f;
            a0 = fmaf(f, __uint_as_float(g.x << 16), a0);
            a1 = fmaf(f, __uint_as_float(g.x & 0xFFFF0000u), a1);
            a2 = fmaf(f, __uint_as_float(g.y << 16), a2);
            a3 = fmaf(f, __uint_as_float(g.y & 0xFFFF0000u), a3);
        }
        float es = es0 + es1;
        a0 += b0; a1 += b1; a2 += b2; a3 += b3;
        es += __shfl_xor(es, 16, 64); es += __shfl_xor(es, 32, 64);
        a0 += __shfl_xor(a0, 16, 64); a0 += __shfl_xor(a0, 32, 64);
        a1 += __shfl_xor(a1, 16, 64); a1 += __shfl_xor(a1, 32, 64);
        a2 += __shfl_xor(a2, 16, 64); a2 += __shfl_xor(a2, 32, 64);
        a3 += __shfl_xor(a3, 16, 64); a3 += __shfl_xor(a3, 32, 64);
        const int n = n0 + ln;
        if (e16 == 0 && n < NN) {
            float inv = 1.f / (es + 1e-12f);
            float4 o = make_float4(a0 * inv, a1 * inv, a2 * inv, a3 * inv);
            *(float4*)&out[(size_t)n * OUTD + c16 * 4] = o;
        }
    }
}

// ---------------------------------------------------------------------------
extern "C" void kernel_launch(void* const* d_in, const int* in_sizes, int n_in,
                              void* d_out, int out_size, void* d_ws, size_t ws_size,
                              hipStream_t stream) {
    const float* x  = (const float*)d_in[0];
    const int*   ei = (const int*)d_in[1];    // (2,E): [0..E)=src, [E..2E)=dst
    const float* W  = (const float*)d_in[2];
    const float* b  = (const float*)d_in[3];
    const float* a  = (const float*)d_in[4];
    float* out = (float*)d_out;

    // workspace layout (~32 MB)
    ushort*   nbuf2 = (ushort*)d_ws;                      // N*64 bf16 = 6.4 MB
    float*    s_src = (float*)(nbuf2 + (size_t)NN * OUTD);// N
    float*    s_dst = s_src + NN;                         // N
    int*      gcur1 = (int*)(s_dst + NN);                 // NC*16
    int*      gcur2 = gcur1 + NC * 16;                    // NFINE*16
    unsigned* ebuf1 = (unsigned*)(gcur2 + NFINE * 16);    // NC*CAP1   = 6.9 MB
    uint2*    ebuf2 = (uint2*)(ebuf1 + (size_t)NC * CAP1);// NFINE*CAP*8 = 17.6 MB

    hipMemsetAsync(gcur1, 0, (NC + NFINE) * 16 * sizeof(int), stream);
    fused_lincoarse_kernel<<<NBLK1 + NLIN, 256, 0, stream>>>(
        x, W, b, a, ei, gcur1, ebuf1, nbuf2, s_src, s_dst);
    finebin_kernel<<<NC * NSPLIT, 256, 0, stream>>>(
        ebuf1, gcur1, s_src, s_dst, gcur2, ebuf2);
    aggregate_kernel<<<NB, 256, 0, stream>>>(ebuf2, gcur2, nbuf2, out);
}

// Round 10
// 145.277 us; speedup vs baseline: 1.0197x; 1.0197x over previous
//
#include <hip/hip_runtime.h>
#include <hip/hip_bf16.h>

#define NN    50000
#define EE    1600000
#define IND   128
#define OUTD  64
#define SLOPE 0.1f

// fine buckets (aggregate granularity)
#define BSH    5                   // log2(nodes per fine bucket)
#define BW     32                  // nodes per fine bucket
#define NB     1564                // ceil(NN / 32) aggregate blocks
#define NFINE  1568                // NC * 8 fine regions allocated
#define CAP    1408                // fine capacity: mean 1024 + 12 sigma
#define CAPT   6                   // ceil(CAP/256) register stash bound
// coarse buckets
#define CSH    8                   // log2(nodes per coarse bucket)
#define NC     196                 // ceil(NN / 256)
#define CAP1   8832                // coarse capacity: mean 8192 + 7 sigma
#define NBLK1  500
#define CHUNK1 (EE / NBLK1)        // 3200 edges per coarse block
#define NSPLIT 4
#define SCAP   (CAP1 / NSPLIT)     // 2208: deterministic stage bound
#define NLIN   (NN / 16)           // 3125 linear blocks

typedef __attribute__((ext_vector_type(8))) short short8;
typedef __attribute__((ext_vector_type(4))) float float4v;

// ---------------------------------------------------------------------------
// Fused K1: blocks [0,NBLK1) = coarse bin; blocks [NBLK1, NBLK1+NLIN) = MFMA
// linear. Independent workloads on different pipes (VMEM-atomic vs MFMA) —
// fusing overlaps them across CUs in one dispatch. Barriers are
// block-uniform (branch on blockIdx only). [R2-verified best: 145.4 us]
// ---------------------------------------------------------------------------
union SMem {
    struct {
        ushort xs[16 * 136];        // x tile bf16 (pad 8/row)
        ushort wt[64 * 136];        // W bf16
        float  newt[16 * 68];       // fp32 out tile (pad 4)
    } lin;
    int h[NC];                      // coarse histogram/cursors
};

__global__ __launch_bounds__(256) void fused_lincoarse_kernel(
    const float* __restrict__ x, const float* __restrict__ W,
    const float* __restrict__ bias, const float* __restrict__ a,
    const int* __restrict__ ei, int* __restrict__ gcur1,
    unsigned* __restrict__ ebuf1,
    ushort* __restrict__ nbuf2, float* __restrict__ s_src, float* __restrict__ s_dst)
{
    __shared__ SMem sm;
    const int tid = threadIdx.x;

    if (blockIdx.x < NBLK1) {
        // ----- coarse bin: 196 buckets of 256 nodes; runs ~16 = full lines
        int* h = sm.h;
        for (int i = tid; i < NC; i += 256) h[i] = 0;
        __syncthreads();
        const int base = blockIdx.x * CHUNK1;
        const int4* s4p = (const int4*)(ei + base);
        for (int i = tid; i < CHUNK1 / 4; i += 256) {
            int4 s4 = s4p[i];
            atomicAdd(&h[s4.x >> CSH], 1);
            atomicAdd(&h[s4.y >> CSH], 1);
            atomicAdd(&h[s4.z >> CSH], 1);
            atomicAdd(&h[s4.w >> CSH], 1);
        }
        __syncthreads();
        for (int i = tid; i < NC; i += 256) {
            int c = h[i];
            if (c) h[i] = i * CAP1 + atomicAdd(&gcur1[i * 16], c);
        }
        __syncthreads();
        const int4* d4p = (const int4*)(ei + EE + base);
        for (int i = tid; i < CHUNK1 / 4; i += 256) {
            int4 s4 = s4p[i];
            int4 d4 = d4p[i];
            int p0 = atomicAdd(&h[s4.x >> CSH], 1);
            int p1 = atomicAdd(&h[s4.y >> CSH], 1);
            int p2 = atomicAdd(&h[s4.z >> CSH], 1);
            int p3 = atomicAdd(&h[s4.w >> CSH], 1);
            ebuf1[p0] = ((unsigned)(s4.x & 255) << 16) | (unsigned)d4.x;
            ebuf1[p1] = ((unsigned)(s4.y & 255) << 16) | (unsigned)d4.y;
            ebuf1[p2] = ((unsigned)(s4.z & 255) << 16) | (unsigned)d4.z;
            ebuf1[p3] = ((unsigned)(s4.w & 255) << 16) | (unsigned)d4.w;
        }
        return;
    }

    // ----- MFMA linear: new = x@W.T + b, bf16 out + fused score dots
    const int node0 = (blockIdx.x - NBLK1) * 16;
    const float4* W4 = (const float4*)W;
    #pragma unroll
    for (int i = 0; i < 8; ++i) {
        int idx = tid + i * 256;
        float4 wv = W4[idx];
        int n = idx >> 5, k = (idx & 31) * 4;
        ushort4 pk; __hip_bfloat16 h;
        h = __float2bfloat16(wv.x); pk.x = *(ushort*)&h;
        h = __float2bfloat16(wv.y); pk.y = *(ushort*)&h;
        h = __float2bfloat16(wv.z); pk.z = *(ushort*)&h;
        h = __float2bfloat16(wv.w); pk.w = *(ushort*)&h;
        *(ushort4*)&sm.lin.wt[n * 136 + k] = pk;
    }
    const float4* x4 = (const float4*)(x + (size_t)node0 * IND);
    #pragma unroll
    for (int i = 0; i < 2; ++i) {
        int idx = tid + i * 256;
        float4 xv = x4[idx];
        int r = idx >> 5, cc = (idx & 31) * 4;
        ushort4 pk; __hip_bfloat16 h;
        h = __float2bfloat16(xv.x); pk.x = *(ushort*)&h;
        h = __float2bfloat16(xv.y); pk.y = *(ushort*)&h;
        h = __float2bfloat16(xv.z); pk.z = *(ushort*)&h;
        h = __float2bfloat16(xv.w); pk.w = *(ushort*)&h;
        *(ushort4*)&sm.lin.xs[r * 136 + cc] = pk;
    }
    __syncthreads();

    const int w    = tid >> 6;
    const int lane = tid & 63;
    const int q    = lane >> 4;
    const int m16  = lane & 15;
    float4v acc = {0.f, 0.f, 0.f, 0.f};
    #pragma unroll
    for (int kk = 0; kk < IND; kk += 32) {
        short8 af = *(const short8*)&sm.lin.xs[m16 * 136 + kk + q * 8];
        short8 bf = *(const short8*)&sm.lin.wt[(w * 16 + m16) * 136 + kk + q * 8];
        acc = __builtin_amdgcn_mfma_f32_16x16x32_bf16(af, bf, acc, 0, 0, 0);
    }
    const float bv = bias[w * 16 + m16];
    #pragma unroll
    for (int r = 0; r < 4; ++r)         // D: col=lane&15, row=quad*4+r
        sm.lin.newt[(q * 4 + r) * 68 + w * 16 + m16] = acc[r] + bv;
    __syncthreads();

    const int nl = tid >> 4;
    const int jg = tid & 15;
    const int j0 = jg * 4;
    float4 va = *(const float4*)&sm.lin.newt[nl * 68 + j0];
    const int n = node0 + nl;
    ushort4 pk;
    { __hip_bfloat16 h;
      h = __float2bfloat16(va.x); pk.x = *(ushort*)&h;
      h = __float2bfloat16(va.y); pk.y = *(ushort*)&h;
      h = __float2bfloat16(va.z); pk.z = *(ushort*)&h;
      h = __float2bfloat16(va.w); pk.w = *(ushort*)&h; }
    *(ushort4*)&nbuf2[(size_t)n * OUTD + j0] = pk;

    float ss = va.x * a[j0]        + va.y * a[j0 + 1]
             + va.z * a[j0 + 2]    + va.w * a[j0 + 3];
    float sd = va.x * a[OUTD + j0]     + va.y * a[OUTD + j0 + 1]
             + va.z * a[OUTD + j0 + 2] + va.w * a[OUTD + j0 + 3];
    #pragma unroll
    for (int m = 1; m < 16; m <<= 1) {
        ss += __shfl_xor(ss, m, 64);
        sd += __shfl_xor(sd, m, 64);
    }
    if (jg == 0) { s_src[n] = ss; s_dst[n] = sd; }
}

// ---------------------------------------------------------------------------
// Pass 2: fine bin. 4 splits per coarse bucket. LDS stage sort, 8 global
// atomics/block, fully-coalesced global writes. [R2-verified]
// ---------------------------------------------------------------------------
__global__ __launch_bounds__(256) void finebin_kernel(
    const unsigned* __restrict__ ebuf1, const int* __restrict__ gcur1,
    int* __restrict__ gcur2, unsigned* __restrict__ ebuf2)
{
    __shared__ unsigned stage[SCAP];
    __shared__ int h[8], lofs[8], grun[8], cur[8];
    const int tid = threadIdx.x;
    const int c   = blockIdx.x >> 2;
    const int sp  = blockIdx.x & 3;
    const int cnt1 = gcur1[c * 16];
    const int seg  = (cnt1 + NSPLIT - 1) / NSPLIT;
    const int lo   = sp * seg;
    const int m    = max(0, min(cnt1, lo + seg) - lo);
    if (tid < 8) h[tid] = 0;
    __syncthreads();
    const unsigned* eb = ebuf1 + (size_t)c * CAP1 + lo;
    for (int i = tid; i < m; i += 256)
        atomicAdd(&h[eb[i] >> 21], 1);          // sub = bits 21..23
    __syncthreads();
    if (tid == 0) {
        int run = 0;
        #pragma unroll
        for (int f = 0; f < 8; ++f) { lofs[f] = run; run += h[f]; }
    }
    __syncthreads();
    if (tid < 8) {
        cur[tid]  = lofs[tid];
        grun[tid] = atomicAdd(&gcur2[(c * 8 + tid) * 16], h[tid]);
    }
    __syncthreads();
    for (int i = tid; i < m; i += 256) {
        unsigned e = eb[i];
        int pos = atomicAdd(&cur[e >> 21], 1);
        stage[pos] = (((e >> 16) & 31u) << 16) | (e & 0xFFFFu);
    }
    __syncthreads();
    #pragma unroll 1
    for (int f = 0; f < 8; ++f) {
        const int cf = h[f];
        unsigned* dst = ebuf2 + (size_t)(c * 8 + f) * CAP + grun[f];
        const unsigned* sp2 = stage + lofs[f];
        for (int i = tid; i < cf; i += 256) dst[i] = sp2[i];   // coalesced
    }
}

// ---------------------------------------------------------------------------
// Fused aggregate v7 (R2-verified best): one block per 32-node fine bucket.
// Static register-stash indexing (unrolled k<CAPT, i=tid+k*256) keeps er/evr
// in VGPRs and overlaps independent s_dst gathers; phase D has a 32-edge
// stage (8 pairs + 8 nbufq gathers in flight per lane) cascading 32->16->4.
// ---------------------------------------------------------------------------
__global__ __launch_bounds__(256) void aggregate_kernel(
    const unsigned* __restrict__ ebuf, const int* __restrict__ gcur,
    const ushort* __restrict__ nbuf2,
    const float* __restrict__ s_src, const float* __restrict__ s_dst,
    float* __restrict__ out)
{
    __shared__ uint2 pairs[CAP];        // {d, bits(ev)} sorted by node
    __shared__ float ssL[BW];
    __shared__ int cntL[BW], ofs[BW], cur[BW];
    const int tid  = threadIdx.x;
    const int wid  = tid >> 6;
    const int lane = tid & 63;
    const int b    = blockIdx.x;
    const int n0   = b << BSH;
    const uint2* __restrict__ nbufq = (const uint2*)nbuf2;  // row = 16 uint2

    if (tid < BW) {
        int n = n0 + tid;
        ssL[tid]  = (n < NN) ? s_src[n] : 0.f;
        cntL[tid] = 0;
    }
    __syncthreads();

    const int cnt = gcur[b * 16];
    const unsigned* eb = ebuf + (size_t)b * CAP;

    unsigned er[CAPT]; float evr[CAPT];
    #pragma unroll
    for (int k = 0; k < CAPT; ++k) {              // lane-parallel exp, static idx
        int i = tid + k * 256;
        if (i < cnt) {
            unsigned e = eb[i];
            er[k] = e;
            int d  = e & 0xFFFFu;
            int ln = e >> 16;
            float sc = ssL[ln] + s_dst[d];
            float lr = sc > 0.f ? sc : SLOPE * sc;
            evr[k] = __expf(lr);
            atomicAdd(&cntL[ln], 1);
        }
    }
    __syncthreads();

    if (wid == 0) {                               // 32-ctr exclusive scan
        int c = (lane < BW) ? cntL[lane] : 0;
        int sc = c;
        #pragma unroll
        for (int m = 1; m < BW; m <<= 1) {
            int v = __shfl_up(sc, m, 64);
            if (lane >= m) sc += v;
        }
        if (lane < BW) { ofs[lane] = sc - c; cur[lane] = sc - c; }
    }
    __syncthreads();

    #pragma unroll
    for (int k = 0; k < CAPT; ++k) {              // sorted LDS scatter, static idx
        int i = tid + k * 256;
        if (i < cnt) {
            int ln = er[k] >> 16;
            int pos = atomicAdd(&cur[ln], 1);
            pairs[pos] = make_uint2(er[k] & 0xFFFFu, __float_as_uint(evr[k]));
        }
    }
    __syncthreads();

    const int e16 = lane >> 4;                    // quarter: edge offset
    const int c16 = lane & 15;                    // 4-dim group (uint2)

    #pragma unroll 1
    for (int t = 0; t < BW / 4; ++t) {            // wave's 8 nodes
        const int ln  = wid * (BW / 4) + t;
        const int beg = ofs[ln];
        const int len = cntL[ln];

        float a0 = 0.f, a1 = 0.f, a2 = 0.f, a3 = 0.f, es = 0.f;
        int j = 0;
        for (; j + 32 <= len; j += 32) {          // 32 edges: 8 per quarter
            uint2 pA = pairs[beg + j + 0  + e16];
            uint2 pB = pairs[beg + j + 4  + e16];
            uint2 pC = pairs[beg + j + 8  + e16];
            uint2 pD = pairs[beg + j + 12 + e16];
            uint2 pE = pairs[beg + j + 16 + e16];
            uint2 pF = pairs[beg + j + 20 + e16];
            uint2 pG = pairs[beg + j + 24 + e16];
            uint2 pH = pairs[beg + j + 28 + e16];
            uint2 gA = nbufq[pA.x * 16 + c16];
            uint2 gB = nbufq[pB.x * 16 + c16];
            uint2 gC = nbufq[pC.x * 16 + c16];
            uint2 gD = nbufq[pD.x * 16 + c16];
            uint2 gE = nbufq[pE.x * 16 + c16];
            uint2 gF = nbufq[pF.x * 16 + c16];
            uint2 gG = nbufq[pG.x * 16 + c16];
            uint2 gH = nbufq[pH.x * 16 + c16];
            float fA = __uint_as_float(pA.y), fB = __uint_as_float(pB.y);
            float fC = __uint_as_float(pC.y), fD = __uint_as_float(pD.y);
            float fE = __uint_as_float(pE.y), fF = __uint_as_float(pF.y);
            float fG = __uint_as_float(pG.y), fH = __uint_as_float(pH.y);
            es += (fA + fB + fC + fD) + (fE + fF + fG + fH);
            a0 = fmaf(fA, __uint_as_float(gA.x << 16), a0);
            a1 = fmaf(fA, __uint_as_float(gA.x & 0xFFFF0000u), a1);
            a2 = fmaf(fA, __uint_as_float(gA.y << 16), a2);
            a3 = fmaf(fA, __uint_as_float(gA.y & 0xFFFF0000u), a3);
            a0 = fmaf(fB, __uint_as_float(gB.x << 16), a0);
            a1 = fmaf(fB, __uint_as_float(gB.x & 0xFFFF0000u), a1);
            a2 = fmaf(fB, __uint_as_float(gB.y << 16), a2);
            a3 = fmaf(fB, __uint_as_float(gB.y & 0xFFFF0000u), a3);
            a0 = fmaf(fC, __uint_as_float(gC.x << 16), a0);
            a1 = fmaf(fC, __uint_as_float(gC.x & 0xFFFF0000u), a1);
            a2 = fmaf(fC, __uint_as_float(gC.y << 16), a2);
            a3 = fmaf(fC, __uint_as_float(gC.y & 0xFFFF0000u), a3);
            a0 = fmaf(fD, __uint_as_float(gD.x << 16), a0);
            a1 = fmaf(fD, __uint_as_float(gD.x & 0xFFFF0000u), a1);
            a2 = fmaf(fD, __uint_as_float(gD.y << 16), a2);
            a3 = fmaf(fD, __uint_as_float(gD.y & 0xFFFF0000u), a3);
            a0 = fmaf(fE, __uint_as_float(gE.x << 16), a0);
            a1 = fmaf(fE, __uint_as_float(gE.x & 0xFFFF0000u), a1);
            a2 = fmaf(fE, __uint_as_float(gE.y << 16), a2);
            a3 = fmaf(fE, __uint_as_float(gE.y & 0xFFFF0000u), a3);
            a0 = fmaf(fF, __uint_as_float(gF.x << 16), a0);
            a1 = fmaf(fF, __uint_as_float(gF.x & 0xFFFF0000u), a1);
            a2 = fmaf(fF, __uint_as_float(gF.y << 16), a2);
            a3 = fmaf(fF, __uint_as_float(gF.y & 0xFFFF0000u), a3);
            a0 = fmaf(fG, __uint_as_float(gG.x << 16), a0);
            a1 = fmaf(fG, __uint_as_float(gG.x & 0xFFFF0000u), a1);
            a2 = fmaf(fG, __uint_as_float(gG.y << 16), a2);
            a3 = fmaf(fG, __uint_as_float(gG.y & 0xFFFF0000u), a3);
            a0 = fmaf(fH, __uint_as_float(gH.x << 16), a0);
            a1 = fmaf(fH, __uint_as_float(gH.x & 0xFFFF0000u), a1);
            a2 = fmaf(fH, __uint_as_float(gH.y << 16), a2);
            a3 = fmaf(fH, __uint_as_float(gH.y & 0xFFFF0000u), a3);
        }
        for (; j + 16 <= len; j += 16) {          // 16 edges: 4 per quarter
            uint2 pA = pairs[beg + j + 0  + e16];
            uint2 pB = pairs[beg + j + 4  + e16];
            uint2 pC = pairs[beg + j + 8  + e16];
            uint2 pD = pairs[beg + j + 12 + e16];
            uint2 gA = nbufq[pA.x * 16 + c16];
            uint2 gB = nbufq[pB.x * 16 + c16];
            uint2 gC = nbufq[pC.x * 16 + c16];
            uint2 gD = nbufq[pD.x * 16 + c16];
            float fA = __uint_as_float(pA.y), fB = __uint_as_float(pB.y);
            float fC = __uint_as_float(pC.y), fD = __uint_as_float(pD.y);
            es += fA + fB + fC + fD;
            a0 = fmaf(fA, __uint_as_float(gA.x << 16), a0);
            a1 = fmaf(fA, __uint_as_float(gA.x & 0xFFFF0000u), a1);
            a2 = fmaf(fA, __uint_as_float(gA.y << 16), a2);
            a3 = fmaf(fA, __uint_as_float(gA.y & 0xFFFF0000u), a3);
            a0 = fmaf(fB, __uint_as_float(gB.x << 16), a0);
            a1 = fmaf(fB, __uint_as_float(gB.x & 0xFFFF0000u), a1);
            a2 = fmaf(fB, __uint_as_float(gB.y << 16), a2);
            a3 = fmaf(fB, __uint_as_float(gB.y & 0xFFFF0000u), a3);
            a0 = fmaf(fC, __uint_as_float(gC.x << 16), a0);
            a1 = fmaf(fC, __uint_as_float(gC.x & 0xFFFF0000u), a1);
            a2 = fmaf(fC, __uint_as_float(gC.y << 16), a2);
            a3 = fmaf(fC, __uint_as_float(gC.y & 0xFFFF0000u), a3);
            a0 = fmaf(fD, __uint_as_float(gD.x << 16), a0);
            a1 = fmaf(fD, __uint_as_float(gD.x & 0xFFFF0000u), a1);
            a2 = fmaf(fD, __uint_as_float(gD.y << 16), a2);
            a3 = fmaf(fD, __uint_as_float(gD.y & 0xFFFF0000u), a3);
        }
        for (; j < len; j += 4) {                 // tail: clamp + mask
            int idx = j + e16;
            uint2 p = pairs[beg + min(idx, len - 1)];
            float f = (idx < len) ? __uint_as_float(p.y) : 0.f;
            uint2 g = nbufq[p.x * 16 + c16];
            es += f;
            a0 = fmaf(f, __uint_as_float(g.x << 16), a0);
            a1 = fmaf(f, __uint_as_float(g.x & 0xFFFF0000u), a1);
            a2 = fmaf(f, __uint_as_float(g.y << 16), a2);
            a3 = fmaf(f, __uint_as_float(g.y & 0xFFFF0000u), a3);
        }
        es += __shfl_xor(es, 16, 64); es += __shfl_xor(es, 32, 64);
        a0 += __shfl_xor(a0, 16, 64); a0 += __shfl_xor(a0, 32, 64);
        a1 += __shfl_xor(a1, 16, 64); a1 += __shfl_xor(a1, 32, 64);
        a2 += __shfl_xor(a2, 16, 64); a2 += __shfl_xor(a2, 32, 64);
        a3 += __shfl_xor(a3, 16, 64); a3 += __shfl_xor(a3, 32, 64);
        const int n = n0 + ln;
        if (e16 == 0 && n < NN) {
            float inv = 1.f / (es + 1e-12f);
            float4 o = make_float4(a0 * inv, a1 * inv, a2 * inv, a3 * inv);
            *(float4*)&out[(size_t)n * OUTD + c16 * 4] = o;
        }
    }
}

// ---------------------------------------------------------------------------
extern "C" void kernel_launch(void* const* d_in, const int* in_sizes, int n_in,
                              void* d_out, int out_size, void* d_ws, size_t ws_size,
                              hipStream_t stream) {
    const float* x  = (const float*)d_in[0];
    const int*   ei = (const int*)d_in[1];    // (2,E): [0..E)=src, [E..2E)=dst
    const float* W  = (const float*)d_in[2];
    const float* b  = (const float*)d_in[3];
    const float* a  = (const float*)d_in[4];
    float* out = (float*)d_out;

    // workspace layout (~23 MB)
    ushort*   nbuf2 = (ushort*)d_ws;                      // N*64 bf16 = 6.4 MB
    float*    s_src = (float*)(nbuf2 + (size_t)NN * OUTD);// N
    float*    s_dst = s_src + NN;                         // N
    int*      gcur1 = (int*)(s_dst + NN);                 // NC*16
    int*      gcur2 = gcur1 + NC * 16;                    // NFINE*16
    unsigned* ebuf1 = (unsigned*)(gcur2 + NFINE * 16);    // NC*CAP1  = 6.9 MB
    unsigned* ebuf2 = ebuf1 + (size_t)NC * CAP1;          // NFINE*CAP = 8.8 MB

    hipMemsetAsync(gcur1, 0, (NC + NFINE) * 16 * sizeof(int), stream);
    fused_lincoarse_kernel<<<NBLK1 + NLIN, 256, 0, stream>>>(
        x, W, b, a, ei, gcur1, ebuf1, nbuf2, s_src, s_dst);
    finebin_kernel<<<NC * NSPLIT, 256, 0, stream>>>(ebuf1, gcur1, gcur2, ebuf2);
    aggregate_kernel<<<NB, 256, 0, stream>>>(ebuf2, gcur2, nbuf2, s_src, s_dst, out);
}